// Round 17
// baseline (177.263 us; speedup 1.0000x reference)
//
#include <hip/hip_runtime.h>
#include <hip/hip_bf16.h>
#include <math.h>

#define NN 8192
#define QSCALE (0.125f * 1.44269504088896f)   // fold 0.125 and log2(e) into Q
#define OSZ (8192*64)
#define NSL 16                                 // pass2 output slices

typedef __attribute__((ext_vector_type(8))) short short8;
typedef __attribute__((ext_vector_type(16))) float f32x16;
typedef __attribute__((ext_vector_type(4))) float f32x4;

union W4 { unsigned u[4]; short8 v; };

__device__ inline unsigned short f2bf(float x) {
  union { float f; unsigned u; } t; t.f = x;
  unsigned r = t.u + 0x7fffu + ((t.u >> 16) & 1u);
  return (unsigned short)(r >> 16);
}
__device__ inline unsigned cvtpk(float lo, float hi) {
  unsigned r;
  asm("v_cvt_pk_bf16_f32 %0, %1, %2" : "=v"(r) : "v"(lo), "v"(hi));
  return r;
}
__device__ inline float fexp2(float x) {
  float r;
  asm("v_exp_f32 %0, %1" : "=v"(r) : "v"(x));
  return r;
}
// async global -> LDS, 16B per lane; LDS dest = base + lane*16 (HW)
__device__ inline void gload16(const float* g, float* l) {
  __builtin_amdgcn_global_load_lds(
      (const __attribute__((address_space(1))) void*)g,
      (__attribute__((address_space(3))) void*)l, 16, 0, 0);
}

// ---------------------------------------------------------------------------
// Kernel 1: Q/K/V/H pre-pack (unchanged).
// ---------------------------------------------------------------------------
__global__ __launch_bounds__(256) void qkv_kernel(
    const float* __restrict__ X, const float* __restrict__ H,
    const float* __restrict__ Qw, const float* __restrict__ Qb,
    const float* __restrict__ Kw, const float* __restrict__ Kb,
    const float* __restrict__ Vw, const float* __restrict__ Vb,
    const float* __restrict__ bng, const float* __restrict__ bnb,
    const float* __restrict__ bnm, const float* __restrict__ bnv,
    unsigned short* __restrict__ QP, unsigned short* __restrict__ KP,
    unsigned short* __restrict__ VP, unsigned short* __restrict__ HP)
{
  int wid = (blockIdx.x * blockDim.x + threadIdx.x) >> 6; // 0..2047
  int d = threadIdx.x & 63;
  float4 w[16];

  for (int fq = 0; fq < 16; fq++) w[fq] = *(const float4*)(Qw + d*64 + fq*4);
  for (int rr = 0; rr < 4; rr++) {
    int r = wid*4 + rr;
    float a = Qb[d];
    for (int fq = 0; fq < 16; fq++) {
      float4 xv = *(const float4*)(X + r*64 + fq*4);
      a += w[fq].x*xv.x + w[fq].y*xv.y + w[fq].z*xv.z + w[fq].w*xv.w;
    }
    float s = a;
    for (int off = 32; off; off >>= 1) s += __shfl_xor(s, off);
    float mean = s * (1.f/64.f);
    float c = a - mean;
    float s2 = c*c;
    for (int off = 32; off; off >>= 1) s2 += __shfl_xor(s2, off);
    float q = c * rsqrtf(s2*(1.f/64.f) + 1e-5f);
    QP[(d>>3)*65536 + r*8 + (d&7)] = f2bf(q * QSCALE);
  }
  for (int fq = 0; fq < 16; fq++) w[fq] = *(const float4*)(Kw + d*64 + fq*4);
  for (int rr = 0; rr < 4; rr++) {
    int r = wid*4 + rr;
    float a = Kb[d];
    for (int fq = 0; fq < 16; fq++) {
      float4 hv = *(const float4*)(H + r*64 + fq*4);
      a += w[fq].x*hv.x + w[fq].y*hv.y + w[fq].z*hv.z + w[fq].w*hv.w;
    }
    float s = a;
    for (int off = 32; off; off >>= 1) s += __shfl_xor(s, off);
    float mean = s * (1.f/64.f);
    float c = a - mean;
    float s2 = c*c;
    for (int off = 32; off; off >>= 1) s2 += __shfl_xor(s2, off);
    float k = c * rsqrtf(s2*(1.f/64.f) + 1e-5f);
    KP[(d>>3)*65536 + r*8 + (d&7)] = f2bf(k);
  }
  for (int fq = 0; fq < 16; fq++) w[fq] = *(const float4*)(Vw + d*64 + fq*4);
  float bscale = rsqrtf(bnv[d] + 1e-5f) * bng[d];
  for (int rr = 0; rr < 4; rr++) {
    int r = wid*4 + rr;
    float a = Vb[d];
    for (int fq = 0; fq < 16; fq++) {
      float4 hv = *(const float4*)(H + r*64 + fq*4);
      a += w[fq].x*hv.x + w[fq].y*hv.y + w[fq].z*hv.z + w[fq].w*hv.w;
    }
    float v = (a - bnm[d]) * bscale + bnb[d];
    VP[(r>>3)*512 + d*8 + (r&7)] = f2bf(v);
    HP[(r>>3)*512 + d*8 + (r&7)] = f2bf(H[r*64 + d]);
  }
}

// ---------------------------------------------------------------------------
// pass 1 (lean): per-column sums of exp2(s*M), + T5 setprio on the MFMA
// cluster (pass1's waves are barrier-free/independent — the regime where
// setprio measured positive).
// ---------------------------------------------------------------------------
__global__ __launch_bounds__(256) void pass1_kernel(
    const float* __restrict__ M, const unsigned short* __restrict__ QP,
    const unsigned short* __restrict__ KP, float* __restrict__ pd)
{
  int tid = threadIdx.x;
  int wj = (blockIdx.x * blockDim.x + tid) >> 6;  // 0..8191
  int lane = tid & 63;
  int l31 = lane & 31, h = lane >> 5;
  int jb = wj & 255, slice = wj >> 8;             // 256 jb x 32 slices
  int j = jb*32 + l31;

  short8 kb[4];
  for (int m = 0; m < 4; m++)
    kb[m] = *(const short8*)(KP + (2*m + h)*65536 + j*8);

  float Mv[16];
  {
    int i0 = slice*8*32;
#pragma unroll
    for (int r = 0; r < 16; r++) {
      int ir = (r&3) + 8*(r>>2) + 4*h;
      Mv[r] = M[(size_t)(i0 + ir)*NN + j];
    }
  }

  float d0 = 0.f, d1 = 0.f, d2 = 0.f, d3 = 0.f;
  for (int t = 0; t < 8; t++) {
    int i0 = (slice*8 + t) * 32;
    float Mn[16];
    if (t < 7) {
      int i1 = i0 + 32;
#pragma unroll
      for (int r = 0; r < 16; r++) {
        int ir = (r&3) + 8*(r>>2) + 4*h;
        Mn[r] = M[(size_t)(i1 + ir)*NN + j];
      }
    }

    f32x16 acc;
    for (int r = 0; r < 16; r++) acc[r] = 0.f;
    __builtin_amdgcn_s_setprio(1);
    for (int m = 0; m < 4; m++) {
      short8 qa = *(const short8*)(QP + (2*m + h)*65536 + (size_t)(i0 + l31)*8);
      acc = __builtin_amdgcn_mfma_f32_32x32x16_bf16(qa, kb[m], acc, 0, 0, 0);
    }
    __builtin_amdgcn_s_setprio(0);

    d0 += fexp2(acc[0]*Mv[0]) + fexp2(acc[4]*Mv[4]) + fexp2(acc[8]*Mv[8])   + fexp2(acc[12]*Mv[12]);
    d1 += fexp2(acc[1]*Mv[1]) + fexp2(acc[5]*Mv[5]) + fexp2(acc[9]*Mv[9])   + fexp2(acc[13]*Mv[13]);
    d2 += fexp2(acc[2]*Mv[2]) + fexp2(acc[6]*Mv[6]) + fexp2(acc[10]*Mv[10]) + fexp2(acc[14]*Mv[14]);
    d3 += fexp2(acc[3]*Mv[3]) + fexp2(acc[7]*Mv[7]) + fexp2(acc[11]*Mv[11]) + fexp2(acc[15]*Mv[15]);

    if (t < 7) {
#pragma unroll
      for (int r = 0; r < 16; r++) Mv[r] = Mn[r];
    }
  }
  float drun = (d0 + d1) + (d2 + d3);
  drun += __shfl_xor(drun, 32);
  if (lane < 32) pd[(size_t)slice*NN + j] = drun;
}

// ---------------------------------------------------------------------------
// combine+vscale fused: csc in LDS, scale VP -> VP2 (unchanged).
// ---------------------------------------------------------------------------
__global__ __launch_bounds__(256) void cv_kernel(
    const float* __restrict__ pd, const unsigned short* __restrict__ VP,
    unsigned short* __restrict__ VP2)
{
  __shared__ float cls[256];
  int tid = threadIdx.x;
  int j = blockIdx.x * 256 + tid;
  float Dv = 0.f;
  for (int s = 0; s < 32; s++) Dv += pd[(size_t)s*NN + j];
  cls[tid] = 0.1f / Dv;
  __syncthreads();

  int base = blockIdx.x * 2048;
#pragma unroll
  for (int k = 0; k < 8; k++) {
    int idx = base + k*256 + tid;
    int lj8 = (k*256 + tid) >> 6;
    const unsigned short* src = VP + (size_t)idx*8;
    unsigned short sv[8];
    *(short8*)sv = *(const short8*)src;
    float f[8];
#pragma unroll
    for (int e = 0; e < 8; e++)
      f[e] = __uint_as_float(((unsigned)sv[e]) << 16) * cls[lj8*8 + e];
    W4 o;
    o.u[0] = cvtpk(f[0], f[1]); o.u[1] = cvtpk(f[2], f[3]);
    o.u[2] = cvtpk(f[4], f[5]); o.u[3] = cvtpk(f[6], f[7]);
    *(short8*)(VP2 + (size_t)idx*8) = o.v;
  }
}

// ---------------------------------------------------------------------------
// pass 2 (R16 structure at HALF WG granularity):
// WG = 2 waves (128 thr), i-block 64 rows; wave wv owns rows wv*32..+31 and
// computes full d=64. Tile 64x32 f32 = 8KB x2buf = 16KB -> ~6 WGs/CU
// concurrent (was 3), barrier syncs only 2 waves. Grid = 128 iblk x 16
// slices = 2048. Per-tm schedule identical to R16 (gload_lds stage tm+1,
// KP prefetch tm+1, setprio MFMA clusters).
// ---------------------------------------------------------------------------
__global__ __launch_bounds__(128) void pass2_kernel(
    const float* __restrict__ M, const unsigned short* __restrict__ QP,
    const unsigned short* __restrict__ KP, const unsigned short* __restrict__ VP2,
    const unsigned short* __restrict__ HP, float* __restrict__ opart)
{
  __shared__ __align__(16) float tile[2][64*32];

  int iblk = blockIdx.x >> 4, slice = blockIdx.x & 15;
  int i0 = iblk * 64;
  int tid = threadIdx.x;
  int lane = tid & 63, wv = tid >> 6;           // wv in {0,1}
  int l31 = lane & 31, h = lane >> 5;
  int irow = wv*32 + l31;                        // wave's row within 64-block
  int i_g = i0 + irow;
  int r7 = irow & 7;

  short8 qb[4];
#pragma unroll
  for (int m = 0; m < 4; m++)
    qb[m] = *(const short8*)(QP + (2*m + h)*65536 + (size_t)i_g*8);

  // staging geometry: wave wv stages its own rows wv*32..+31; 4 instrs x 8 rows
  int rsub = lane >> 3;            // 0..7 row within instr
  int gdst = lane & 7;             // dest granule
  int c0base = slice*512;

  // prologue: stage tile 0
#pragma unroll
  for (int k = 0; k < 4; k++) {
    int rloc = wv*32 + k*8 + rsub;
    int gs = gdst ^ (rloc & 7);
    gload16(M + (size_t)(i0 + rloc)*NN + c0base + gs*4,
            &tile[0][(wv*32 + k*8)*32]);
  }
  __syncthreads();

  // KP prefetch for tm=0
  short8 kcur[4];
#pragma unroll
  for (int m = 0; m < 4; m++)
    kcur[m] = *(const short8*)(KP + (2*m + h)*65536 + (size_t)(c0base + l31)*8);

  f32x16 oaccA, oaccB;
  for (int r = 0; r < 16; r++) { oaccA[r] = 0.f; oaccB[r] = 0.f; }

  for (int tm = 0; tm < 16; tm++) {
    int jt = c0base + tm*32;

    // ---- issue async stage of tile tm+1 (drained at the barrier) ----
    if (tm < 15) {
      int c0 = c0base + (tm+1)*32;
      float* dst = tile[(tm+1) & 1];
#pragma unroll
      for (int k = 0; k < 4; k++) {
        int rloc = wv*32 + k*8 + rsub;
        int gs = gdst ^ (rloc & 7);
        gload16(M + (size_t)(i0 + rloc)*NN + c0 + gs*4,
                &dst[(wv*32 + k*8)*32]);
      }
    }
    const float* mb = tile[tm & 1];

    // ---- prefetch KP frags for tm+1 (hide L2 latency under this tm) ----
    short8 knxt[4];
    if (tm < 15) {
#pragma unroll
      for (int m = 0; m < 4; m++)
        knxt[m] = *(const short8*)(KP + (2*m + h)*65536 + (size_t)(jt + 32 + l31)*8);
    }

    // ---- Mv from LDS: 4 x b128, read-side XOR ----
    f32x4 mv[4];
#pragma unroll
    for (int q = 0; q < 4; q++) {
      int gr = 2*q + h;
      mv[q] = *(const f32x4*)&mb[irow*32 + ((gr ^ r7) << 2)];
    }

    // ---- sacc = K x Q^T (computed once per element) ----
    f32x16 sacc;
    for (int r = 0; r < 16; r++) sacc[r] = 0.f;
    __builtin_amdgcn_s_setprio(1);
#pragma unroll
    for (int m = 0; m < 4; m++)
      sacc = __builtin_amdgcn_mfma_f32_32x32x16_bf16(kcur[m], qb[m], sacc, 0, 0, 0);
    __builtin_amdgcn_s_setprio(0);

    // ---- p = exp2(s*M) (norm folded into V') ----
    float p[16];
#pragma unroll
    for (int q = 0; q < 4; q++) {
      p[4*q+0] = fexp2(sacc[4*q+0] * mv[q][0]);
      p[4*q+1] = fexp2(sacc[4*q+1] * mv[q][1]);
      p[4*q+2] = fexp2(sacc[4*q+2] * mv[q][2]);
      p[4*q+3] = fexp2(sacc[4*q+3] * mv[q][3]);
    }
    unsigned pu[8], mw[8];
#pragma unroll
    for (int k = 0; k < 8; k++) pu[k] = cvtpk(p[2*k], p[2*k+1]);
#pragma unroll
    for (int q = 0; q < 4; q++) {
      mw[2*q]   = cvtpk(mv[q][0], mv[q][1]);
      mw[2*q+1] = cvtpk(mv[q][2], mv[q][3]);
    }

    // ---- half-swaps -> A-frag words ----
    asm volatile("v_permlane32_swap_b32 %0, %1" : "+v"(pu[0]), "+v"(pu[2]));
    asm volatile("v_permlane32_swap_b32 %0, %1" : "+v"(pu[1]), "+v"(pu[3]));
    asm volatile("v_permlane32_swap_b32 %0, %1" : "+v"(pu[4]), "+v"(pu[6]));
    asm volatile("v_permlane32_swap_b32 %0, %1" : "+v"(pu[5]), "+v"(pu[7]));
    asm volatile("v_permlane32_swap_b32 %0, %1" : "+v"(mw[0]), "+v"(mw[2]));
    asm volatile("v_permlane32_swap_b32 %0, %1" : "+v"(mw[1]), "+v"(mw[3]));
    asm volatile("v_permlane32_swap_b32 %0, %1" : "+v"(mw[4]), "+v"(mw[6]));
    asm volatile("v_permlane32_swap_b32 %0, %1" : "+v"(mw[5]), "+v"(mw[7]));

    W4 PA0, PA1, MA0, MA1;
    PA0.u[0] = pu[0]; PA0.u[1] = pu[1]; PA0.u[2] = pu[2]; PA0.u[3] = pu[3];
    PA1.u[0] = pu[4]; PA1.u[1] = pu[5]; PA1.u[2] = pu[6]; PA1.u[3] = pu[7];
    MA0.u[0] = mw[0]; MA0.u[1] = mw[1]; MA0.u[2] = mw[2]; MA0.u[3] = mw[3];
    MA1.u[0] = mw[4]; MA1.u[1] = mw[5]; MA1.u[2] = mw[6]; MA1.u[3] = mw[7];

    // ---- output MFMAs: both d-halves per wave ----
    int j8 = jt >> 3;
    const unsigned short* vb_ = VP2 + (size_t)j8*512 + l31*8;
    const unsigned short* hb_ = HP  + (size_t)j8*512 + l31*8;
    {
      short8 vA1 = *(const short8*)(vb_ + h*512);
      short8 vA2 = *(const short8*)(vb_ + (2 + h)*512);
      short8 hA1 = *(const short8*)(hb_ + h*512);
      short8 hA2 = *(const short8*)(hb_ + (2 + h)*512);
      short8 vB1 = *(const short8*)(vb_ + 256 + h*512);       // d 32..63
      short8 vB2 = *(const short8*)(vb_ + 256 + (2 + h)*512);
      short8 hB1 = *(const short8*)(hb_ + 256 + h*512);
      short8 hB2 = *(const short8*)(hb_ + 256 + (2 + h)*512);
      __builtin_amdgcn_s_setprio(1);
      oaccA = __builtin_amdgcn_mfma_f32_32x32x16_bf16(PA0.v, vA1, oaccA, 0, 0, 0);
      oaccB = __builtin_amdgcn_mfma_f32_32x32x16_bf16(PA0.v, vB1, oaccB, 0, 0, 0);
      oaccA = __builtin_amdgcn_mfma_f32_32x32x16_bf16(PA1.v, vA2, oaccA, 0, 0, 0);
      oaccB = __builtin_amdgcn_mfma_f32_32x32x16_bf16(PA1.v, vB2, oaccB, 0, 0, 0);
      oaccA = __builtin_amdgcn_mfma_f32_32x32x16_bf16(MA0.v, hA1, oaccA, 0, 0, 0);
      oaccB = __builtin_amdgcn_mfma_f32_32x32x16_bf16(MA0.v, hB1, oaccB, 0, 0, 0);
      oaccA = __builtin_amdgcn_mfma_f32_32x32x16_bf16(MA1.v, hA2, oaccA, 0, 0, 0);
      oaccB = __builtin_amdgcn_mfma_f32_32x32x16_bf16(MA1.v, hB2, oaccB, 0, 0, 0);
      __builtin_amdgcn_s_setprio(0);
    }

#pragma unroll
    for (int m = 0; m < 4; m++) kcur[m] = knxt[m];

    __syncthreads();   // tm+1 staged (vmcnt drained), tile tm free
  }

  float* obase = opart + (size_t)slice*OSZ;
#pragma unroll
  for (int r = 0; r < 16; r++) {
    int orow = i0 + wv*32 + (r&3) + 8*(r>>2) + 4*h;
    obase[(size_t)orow*64 + l31]      = oaccA[r];
    obase[(size_t)orow*64 + 32 + l31] = oaccB[r];
  }
}

// ---------------------------------------------------------------------------
// reduce: out = sum over NSL slices of opart
// ---------------------------------------------------------------------------
__global__ __launch_bounds__(256) void reduce_kernel(
    const float* __restrict__ opart, float* __restrict__ out)
{
  int e4 = blockIdx.x * blockDim.x + threadIdx.x;   // 0..131071
  const float4* p = (const float4*)opart;
  float4 a = p[e4];
#pragma unroll
  for (int s = 1; s < NSL; s++) {
    float4 b = p[(size_t)s*(OSZ/4) + e4];
    a.x += b.x; a.y += b.y; a.z += b.z; a.w += b.w;
  }
  ((float4*)out)[e4] = a;
}

// ---------------------------------------------------------------------------
extern "C" void kernel_launch(void* const* d_in, const int* in_sizes, int n_in,
                              void* d_out, int out_size, void* d_ws, size_t ws_size,
                              hipStream_t stream) {
  const float* X   = (const float*)d_in[0];
  const float* H   = (const float*)d_in[1];
  const float* M   = (const float*)d_in[2];
  const float* Qw  = (const float*)d_in[3];
  const float* Qb  = (const float*)d_in[4];
  const float* Kw  = (const float*)d_in[5];
  const float* Kb  = (const float*)d_in[6];
  const float* Vw  = (const float*)d_in[7];
  const float* Vb  = (const float*)d_in[8];
  const float* bng = (const float*)d_in[9];
  const float* bnb = (const float*)d_in[10];
  const float* bnm = (const float*)d_in[11];
  const float* bnv = (const float*)d_in[12];
  float* out = (float*)d_out;

  char* ws = (char*)d_ws;
  const size_t MB = 1024*1024;
  unsigned short* QP  = (unsigned short*)(ws);           // 1 MB
  unsigned short* KP  = (unsigned short*)(ws + 1*MB);
  unsigned short* VP  = (unsigned short*)(ws + 2*MB);
  unsigned short* HP  = (unsigned short*)(ws + 3*MB);
  unsigned short* VP2 = (unsigned short*)(ws + 4*MB);
  float* pd           = (float*)(ws + 5*MB);             // 1 MB
  float* opart        = (float*)(ws + 7*MB);             // 32 MB (16 slices)

  qkv_kernel<<<512, 256, 0, stream>>>(X, H, Qw, Qb, Kw, Kb, Vw, Vb,
                                      bng, bnb, bnm, bnv, QP, KP, VP, HP);
  pass1_kernel<<<2048, 256, 0, stream>>>(M, QP, KP, pd);
  cv_kernel<<<32, 256, 0, stream>>>(pd, VP, VP2);
  pass2_kernel<<<2048, 128, 0, stream>>>(M, QP, KP, VP2, HP, opart);
  reduce_kernel<<<512, 256, 0, stream>>>(opart, out);
}

// Round 18
// 164.850 us; speedup vs baseline: 1.0753x; 1.0753x over previous
//
#include <hip/hip_runtime.h>
#include <hip/hip_bf16.h>
#include <math.h>

#define NN 8192
#define QSCALE (0.125f * 1.44269504088896f)   // fold 0.125 and log2(e) into Q
#define OSZ (8192*64)
#define NSL 16                                 // pass2 output slices

typedef __attribute__((ext_vector_type(8))) short short8;
typedef __attribute__((ext_vector_type(16))) float f32x16;
typedef __attribute__((ext_vector_type(4))) float f32x4;

union W4 { unsigned u[4]; short8 v; };

__device__ inline unsigned short f2bf(float x) {
  union { float f; unsigned u; } t; t.f = x;
  unsigned r = t.u + 0x7fffu + ((t.u >> 16) & 1u);
  return (unsigned short)(r >> 16);
}
__device__ inline unsigned cvtpk(float lo, float hi) {
  unsigned r;
  asm("v_cvt_pk_bf16_f32 %0, %1, %2" : "=v"(r) : "v"(lo), "v"(hi));
  return r;
}
__device__ inline float fexp2(float x) {
  float r;
  asm("v_exp_f32 %0, %1" : "=v"(r) : "v"(x));
  return r;
}
// async global -> LDS, 16B per lane; LDS dest = base + lane*16 (HW)
__device__ inline void gload16(const float* g, float* l) {
  __builtin_amdgcn_global_load_lds(
      (const __attribute__((address_space(1))) void*)g,
      (__attribute__((address_space(3))) void*)l, 16, 0, 0);
}

// ---------------------------------------------------------------------------
// Kernel 1: Q/K/V/H pre-pack (unchanged).
// ---------------------------------------------------------------------------
__global__ __launch_bounds__(256) void qkv_kernel(
    const float* __restrict__ X, const float* __restrict__ H,
    const float* __restrict__ Qw, const float* __restrict__ Qb,
    const float* __restrict__ Kw, const float* __restrict__ Kb,
    const float* __restrict__ Vw, const float* __restrict__ Vb,
    const float* __restrict__ bng, const float* __restrict__ bnb,
    const float* __restrict__ bnm, const float* __restrict__ bnv,
    unsigned short* __restrict__ QP, unsigned short* __restrict__ KP,
    unsigned short* __restrict__ VP, unsigned short* __restrict__ HP)
{
  int wid = (blockIdx.x * blockDim.x + threadIdx.x) >> 6; // 0..2047
  int d = threadIdx.x & 63;
  float4 w[16];

  for (int fq = 0; fq < 16; fq++) w[fq] = *(const float4*)(Qw + d*64 + fq*4);
  for (int rr = 0; rr < 4; rr++) {
    int r = wid*4 + rr;
    float a = Qb[d];
    for (int fq = 0; fq < 16; fq++) {
      float4 xv = *(const float4*)(X + r*64 + fq*4);
      a += w[fq].x*xv.x + w[fq].y*xv.y + w[fq].z*xv.z + w[fq].w*xv.w;
    }
    float s = a;
    for (int off = 32; off; off >>= 1) s += __shfl_xor(s, off);
    float mean = s * (1.f/64.f);
    float c = a - mean;
    float s2 = c*c;
    for (int off = 32; off; off >>= 1) s2 += __shfl_xor(s2, off);
    float q = c * rsqrtf(s2*(1.f/64.f) + 1e-5f);
    QP[(d>>3)*65536 + r*8 + (d&7)] = f2bf(q * QSCALE);
  }
  for (int fq = 0; fq < 16; fq++) w[fq] = *(const float4*)(Kw + d*64 + fq*4);
  for (int rr = 0; rr < 4; rr++) {
    int r = wid*4 + rr;
    float a = Kb[d];
    for (int fq = 0; fq < 16; fq++) {
      float4 hv = *(const float4*)(H + r*64 + fq*4);
      a += w[fq].x*hv.x + w[fq].y*hv.y + w[fq].z*hv.z + w[fq].w*hv.w;
    }
    float s = a;
    for (int off = 32; off; off >>= 1) s += __shfl_xor(s, off);
    float mean = s * (1.f/64.f);
    float c = a - mean;
    float s2 = c*c;
    for (int off = 32; off; off >>= 1) s2 += __shfl_xor(s2, off);
    float k = c * rsqrtf(s2*(1.f/64.f) + 1e-5f);
    KP[(d>>3)*65536 + r*8 + (d&7)] = f2bf(k);
  }
  for (int fq = 0; fq < 16; fq++) w[fq] = *(const float4*)(Vw + d*64 + fq*4);
  float bscale = rsqrtf(bnv[d] + 1e-5f) * bng[d];
  for (int rr = 0; rr < 4; rr++) {
    int r = wid*4 + rr;
    float a = Vb[d];
    for (int fq = 0; fq < 16; fq++) {
      float4 hv = *(const float4*)(H + r*64 + fq*4);
      a += w[fq].x*hv.x + w[fq].y*hv.y + w[fq].z*hv.z + w[fq].w*hv.w;
    }
    float v = (a - bnm[d]) * bscale + bnb[d];
    VP[(r>>3)*512 + d*8 + (r&7)] = f2bf(v);
    HP[(r>>3)*512 + d*8 + (r&7)] = f2bf(H[r*64 + d]);
  }
}

// ---------------------------------------------------------------------------
// pass 1 (lean): per-column sums of exp2(s*M) + setprio (unchanged from R16).
// ---------------------------------------------------------------------------
__global__ __launch_bounds__(256) void pass1_kernel(
    const float* __restrict__ M, const unsigned short* __restrict__ QP,
    const unsigned short* __restrict__ KP, float* __restrict__ pd)
{
  int tid = threadIdx.x;
  int wj = (blockIdx.x * blockDim.x + tid) >> 6;  // 0..8191
  int lane = tid & 63;
  int l31 = lane & 31, h = lane >> 5;
  int jb = wj & 255, slice = wj >> 8;             // 256 jb x 32 slices
  int j = jb*32 + l31;

  short8 kb[4];
  for (int m = 0; m < 4; m++)
    kb[m] = *(const short8*)(KP + (2*m + h)*65536 + j*8);

  float Mv[16];
  {
    int i0 = slice*8*32;
#pragma unroll
    for (int r = 0; r < 16; r++) {
      int ir = (r&3) + 8*(r>>2) + 4*h;
      Mv[r] = M[(size_t)(i0 + ir)*NN + j];
    }
  }

  float d0 = 0.f, d1 = 0.f, d2 = 0.f, d3 = 0.f;
  for (int t = 0; t < 8; t++) {
    int i0 = (slice*8 + t) * 32;
    float Mn[16];
    if (t < 7) {
      int i1 = i0 + 32;
#pragma unroll
      for (int r = 0; r < 16; r++) {
        int ir = (r&3) + 8*(r>>2) + 4*h;
        Mn[r] = M[(size_t)(i1 + ir)*NN + j];
      }
    }

    f32x16 acc;
    for (int r = 0; r < 16; r++) acc[r] = 0.f;
    __builtin_amdgcn_s_setprio(1);
    for (int m = 0; m < 4; m++) {
      short8 qa = *(const short8*)(QP + (2*m + h)*65536 + (size_t)(i0 + l31)*8);
      acc = __builtin_amdgcn_mfma_f32_32x32x16_bf16(qa, kb[m], acc, 0, 0, 0);
    }
    __builtin_amdgcn_s_setprio(0);

    d0 += fexp2(acc[0]*Mv[0]) + fexp2(acc[4]*Mv[4]) + fexp2(acc[8]*Mv[8])   + fexp2(acc[12]*Mv[12]);
    d1 += fexp2(acc[1]*Mv[1]) + fexp2(acc[5]*Mv[5]) + fexp2(acc[9]*Mv[9])   + fexp2(acc[13]*Mv[13]);
    d2 += fexp2(acc[2]*Mv[2]) + fexp2(acc[6]*Mv[6]) + fexp2(acc[10]*Mv[10]) + fexp2(acc[14]*Mv[14]);
    d3 += fexp2(acc[3]*Mv[3]) + fexp2(acc[7]*Mv[7]) + fexp2(acc[11]*Mv[11]) + fexp2(acc[15]*Mv[15]);

    if (t < 7) {
#pragma unroll
      for (int r = 0; r < 16; r++) Mv[r] = Mn[r];
    }
  }
  float drun = (d0 + d1) + (d2 + d3);
  drun += __shfl_xor(drun, 32);
  if (lane < 32) pd[(size_t)slice*NN + j] = drun;
}

// ---------------------------------------------------------------------------
// combine+vscale fused: csc in LDS, scale VP -> VP2 (unchanged).
// ---------------------------------------------------------------------------
__global__ __launch_bounds__(256) void cv_kernel(
    const float* __restrict__ pd, const unsigned short* __restrict__ VP,
    unsigned short* __restrict__ VP2)
{
  __shared__ float cls[256];
  int tid = threadIdx.x;
  int j = blockIdx.x * 256 + tid;
  float Dv = 0.f;
  for (int s = 0; s < 32; s++) Dv += pd[(size_t)s*NN + j];
  cls[tid] = 0.1f / Dv;
  __syncthreads();

  int base = blockIdx.x * 2048;
#pragma unroll
  for (int k = 0; k < 8; k++) {
    int idx = base + k*256 + tid;
    int lj8 = (k*256 + tid) >> 6;
    const unsigned short* src = VP + (size_t)idx*8;
    unsigned short sv[8];
    *(short8*)sv = *(const short8*)src;
    float f[8];
#pragma unroll
    for (int e = 0; e < 8; e++)
      f[e] = __uint_as_float(((unsigned)sv[e]) << 16) * cls[lj8*8 + e];
    W4 o;
    o.u[0] = cvtpk(f[0], f[1]); o.u[1] = cvtpk(f[2], f[3]);
    o.u[2] = cvtpk(f[4], f[5]); o.u[3] = cvtpk(f[6], f[7]);
    *(short8*)(VP2 + (size_t)idx*8) = o.v;
  }
}

// ---------------------------------------------------------------------------
// pass 2 (R16 base + sacc software-pipelined one iteration ahead):
// sacc depends only on KP/qb (not the M tile), so sacc(tm+1) is computed at
// the END of body tm (knxt loads have the whole exp/output phase to land),
// re-accumulating into saccC's registers (dead after the exp). Critical path
// per tm becomes: barrier -> ds_read Mv -> exp -> pack -> output MFMAs.
// WG = 4 waves, i-block 128 rows, wave owns 32 rows + full d=64. Grid 1024.
// ---------------------------------------------------------------------------
__global__ __launch_bounds__(256) void pass2_kernel(
    const float* __restrict__ M, const unsigned short* __restrict__ QP,
    const unsigned short* __restrict__ KP, const unsigned short* __restrict__ VP2,
    const unsigned short* __restrict__ HP, float* __restrict__ opart)
{
  __shared__ __align__(16) float tile[2][128*32];

  int iblk = blockIdx.x >> 4, slice = blockIdx.x & 15;
  int i0 = iblk * 128;
  int tid = threadIdx.x;
  int lane = tid & 63, wv = tid >> 6;
  int l31 = lane & 31, h = lane >> 5;
  int irow = wv*32 + l31;          // wave's row within the 128-block
  int i_g = i0 + irow;
  int r7 = irow & 7;

  short8 qb[4];
#pragma unroll
  for (int m = 0; m < 4; m++)
    qb[m] = *(const short8*)(QP + (2*m + h)*65536 + (size_t)i_g*8);

  // staging geometry: wave wv stages its own rows wv*32..+31; 4 instrs x 8 rows
  int rsub = lane >> 3;            // 0..7 row within instr
  int gdst = lane & 7;             // dest granule
  int c0base = slice*512;

  // prologue: stage tile 0
#pragma unroll
  for (int k = 0; k < 4; k++) {
    int rloc = wv*32 + k*8 + rsub;
    int gs = gdst ^ (rloc & 7);
    gload16(M + (size_t)(i0 + rloc)*NN + c0base + gs*4,
            &tile[0][(wv*32 + k*8)*32]);
  }

  // prologue: KP frags for tm=0 and sacc(0)
  f32x16 saccC;
  for (int r = 0; r < 16; r++) saccC[r] = 0.f;
  {
    short8 k0[4];
#pragma unroll
    for (int m = 0; m < 4; m++)
      k0[m] = *(const short8*)(KP + (2*m + h)*65536 + (size_t)(c0base + l31)*8);
    __builtin_amdgcn_s_setprio(1);
#pragma unroll
    for (int m = 0; m < 4; m++)
      saccC = __builtin_amdgcn_mfma_f32_32x32x16_bf16(k0[m], qb[m], saccC, 0, 0, 0);
    __builtin_amdgcn_s_setprio(0);
  }
  __syncthreads();

  f32x16 oaccA, oaccB;
  for (int r = 0; r < 16; r++) { oaccA[r] = 0.f; oaccB[r] = 0.f; }

  for (int tm = 0; tm < 16; tm++) {
    int jt = c0base + tm*32;

    // ---- issue async stage of tile tm+1 (drained at the barrier) ----
    if (tm < 15) {
      int c0 = c0base + (tm+1)*32;
      float* dst = tile[(tm+1) & 1];
#pragma unroll
      for (int k = 0; k < 4; k++) {
        int rloc = wv*32 + k*8 + rsub;
        int gs = gdst ^ (rloc & 7);
        gload16(M + (size_t)(i0 + rloc)*NN + c0 + gs*4,
                &dst[(wv*32 + k*8)*32]);
      }
    }
    const float* mb = tile[tm & 1];

    // ---- issue KP frag loads for tm+1 (land during exp/output phase) ----
    short8 knxt[4];
    if (tm < 15) {
#pragma unroll
      for (int m = 0; m < 4; m++)
        knxt[m] = *(const short8*)(KP + (2*m + h)*65536 + (size_t)(jt + 32 + l31)*8);
    }

    // ---- Mv from LDS: 4 x b128, read-side XOR ----
    f32x4 mv[4];
#pragma unroll
    for (int q = 0; q < 4; q++) {
      int gr = 2*q + h;
      mv[q] = *(const f32x4*)&mb[irow*32 + ((gr ^ r7) << 2)];
    }

    // ---- p = exp2(saccC*M) — sacc already computed last iteration ----
    float p[16];
#pragma unroll
    for (int q = 0; q < 4; q++) {
      p[4*q+0] = fexp2(saccC[4*q+0] * mv[q][0]);
      p[4*q+1] = fexp2(saccC[4*q+1] * mv[q][1]);
      p[4*q+2] = fexp2(saccC[4*q+2] * mv[q][2]);
      p[4*q+3] = fexp2(saccC[4*q+3] * mv[q][3]);
    }
    unsigned pu[8], mw[8];
#pragma unroll
    for (int k = 0; k < 8; k++) pu[k] = cvtpk(p[2*k], p[2*k+1]);
#pragma unroll
    for (int q = 0; q < 4; q++) {
      mw[2*q]   = cvtpk(mv[q][0], mv[q][1]);
      mw[2*q+1] = cvtpk(mv[q][2], mv[q][3]);
    }

    // ---- half-swaps -> A-frag words ----
    asm volatile("v_permlane32_swap_b32 %0, %1" : "+v"(pu[0]), "+v"(pu[2]));
    asm volatile("v_permlane32_swap_b32 %0, %1" : "+v"(pu[1]), "+v"(pu[3]));
    asm volatile("v_permlane32_swap_b32 %0, %1" : "+v"(pu[4]), "+v"(pu[6]));
    asm volatile("v_permlane32_swap_b32 %0, %1" : "+v"(pu[5]), "+v"(pu[7]));
    asm volatile("v_permlane32_swap_b32 %0, %1" : "+v"(mw[0]), "+v"(mw[2]));
    asm volatile("v_permlane32_swap_b32 %0, %1" : "+v"(mw[1]), "+v"(mw[3]));
    asm volatile("v_permlane32_swap_b32 %0, %1" : "+v"(mw[4]), "+v"(mw[6]));
    asm volatile("v_permlane32_swap_b32 %0, %1" : "+v"(mw[5]), "+v"(mw[7]));

    W4 PA0, PA1, MA0, MA1;
    PA0.u[0] = pu[0]; PA0.u[1] = pu[1]; PA0.u[2] = pu[2]; PA0.u[3] = pu[3];
    PA1.u[0] = pu[4]; PA1.u[1] = pu[5]; PA1.u[2] = pu[6]; PA1.u[3] = pu[7];
    MA0.u[0] = mw[0]; MA0.u[1] = mw[1]; MA0.u[2] = mw[2]; MA0.u[3] = mw[3];
    MA1.u[0] = mw[4]; MA1.u[1] = mw[5]; MA1.u[2] = mw[6]; MA1.u[3] = mw[7];

    // ---- output MFMAs: both d-halves per wave ----
    int j8 = jt >> 3;
    const unsigned short* vb_ = VP2 + (size_t)j8*512 + l31*8;
    const unsigned short* hb_ = HP  + (size_t)j8*512 + l31*8;
    {
      short8 vA1 = *(const short8*)(vb_ + h*512);
      short8 vA2 = *(const short8*)(vb_ + (2 + h)*512);
      short8 hA1 = *(const short8*)(hb_ + h*512);
      short8 hA2 = *(const short8*)(hb_ + (2 + h)*512);
      short8 vB1 = *(const short8*)(vb_ + 256 + h*512);       // d 32..63
      short8 vB2 = *(const short8*)(vb_ + 256 + (2 + h)*512);
      short8 hB1 = *(const short8*)(hb_ + 256 + h*512);
      short8 hB2 = *(const short8*)(hb_ + 256 + (2 + h)*512);
      __builtin_amdgcn_s_setprio(1);
      oaccA = __builtin_amdgcn_mfma_f32_32x32x16_bf16(PA0.v, vA1, oaccA, 0, 0, 0);
      oaccB = __builtin_amdgcn_mfma_f32_32x32x16_bf16(PA0.v, vB1, oaccB, 0, 0, 0);
      oaccA = __builtin_amdgcn_mfma_f32_32x32x16_bf16(PA1.v, vA2, oaccA, 0, 0, 0);
      oaccB = __builtin_amdgcn_mfma_f32_32x32x16_bf16(PA1.v, vB2, oaccB, 0, 0, 0);
      oaccA = __builtin_amdgcn_mfma_f32_32x32x16_bf16(MA0.v, hA1, oaccA, 0, 0, 0);
      oaccB = __builtin_amdgcn_mfma_f32_32x32x16_bf16(MA0.v, hB1, oaccB, 0, 0, 0);
      oaccA = __builtin_amdgcn_mfma_f32_32x32x16_bf16(MA1.v, hA2, oaccA, 0, 0, 0);
      oaccB = __builtin_amdgcn_mfma_f32_32x32x16_bf16(MA1.v, hB2, oaccB, 0, 0, 0);
      __builtin_amdgcn_s_setprio(0);
    }

    // ---- compute sacc(tm+1) into saccC's (now dead) registers ----
    if (tm < 15) {
      for (int r = 0; r < 16; r++) saccC[r] = 0.f;
      __builtin_amdgcn_s_setprio(1);
#pragma unroll
      for (int m = 0; m < 4; m++)
        saccC = __builtin_amdgcn_mfma_f32_32x32x16_bf16(knxt[m], qb[m], saccC, 0, 0, 0);
      __builtin_amdgcn_s_setprio(0);
    }

    __syncthreads();   // tm+1 staged (vmcnt drained), tile tm free
  }

  float* obase = opart + (size_t)slice*OSZ;
#pragma unroll
  for (int r = 0; r < 16; r++) {
    int orow = i0 + wv*32 + (r&3) + 8*(r>>2) + 4*h;
    obase[(size_t)orow*64 + l31]      = oaccA[r];
    obase[(size_t)orow*64 + 32 + l31] = oaccB[r];
  }
}

// ---------------------------------------------------------------------------
// reduce: out = sum over NSL slices of opart
// ---------------------------------------------------------------------------
__global__ __launch_bounds__(256) void reduce_kernel(
    const float* __restrict__ opart, float* __restrict__ out)
{
  int e4 = blockIdx.x * blockDim.x + threadIdx.x;   // 0..131071
  const float4* p = (const float4*)opart;
  float4 a = p[e4];
#pragma unroll
  for (int s = 1; s < NSL; s++) {
    float4 b = p[(size_t)s*(OSZ/4) + e4];
    a.x += b.x; a.y += b.y; a.z += b.z; a.w += b.w;
  }
  ((float4*)out)[e4] = a;
}

// ---------------------------------------------------------------------------
extern "C" void kernel_launch(void* const* d_in, const int* in_sizes, int n_in,
                              void* d_out, int out_size, void* d_ws, size_t ws_size,
                              hipStream_t stream) {
  const float* X   = (const float*)d_in[0];
  const float* H   = (const float*)d_in[1];
  const float* M   = (const float*)d_in[2];
  const float* Qw  = (const float*)d_in[3];
  const float* Qb  = (const float*)d_in[4];
  const float* Kw  = (const float*)d_in[5];
  const float* Kb  = (const float*)d_in[6];
  const float* Vw  = (const float*)d_in[7];
  const float* Vb  = (const float*)d_in[8];
  const float* bng = (const float*)d_in[9];
  const float* bnb = (const float*)d_in[10];
  const float* bnm = (const float*)d_in[11];
  const float* bnv = (const float*)d_in[12];
  float* out = (float*)d_out;

  char* ws = (char*)d_ws;
  const size_t MB = 1024*1024;
  unsigned short* QP  = (unsigned short*)(ws);           // 1 MB
  unsigned short* KP  = (unsigned short*)(ws + 1*MB);
  unsigned short* VP  = (unsigned short*)(ws + 2*MB);
  unsigned short* HP  = (unsigned short*)(ws + 3*MB);
  unsigned short* VP2 = (unsigned short*)(ws + 4*MB);
  float* pd           = (float*)(ws + 5*MB);             // 1 MB
  float* opart        = (float*)(ws + 7*MB);             // 32 MB (16 slices)

  qkv_kernel<<<512, 256, 0, stream>>>(X, H, Qw, Qb, Kw, Kb, Vw, Vb,
                                      bng, bnb, bnm, bnv, QP, KP, VP, HP);
  pass1_kernel<<<2048, 256, 0, stream>>>(M, QP, KP, pd);
  cv_kernel<<<32, 256, 0, stream>>>(pd, VP, VP2);
  pass2_kernel<<<1024, 256, 0, stream>>>(M, QP, KP, VP2, HP, opart);
  reduce_kernel<<<512, 256, 0, stream>>>(opart, out);
}